// Round 11
// baseline (78.161 us; speedup 1.0000x reference)
//
#include <hip/hip_runtime.h>

#define EPS 1e-7f
#define LOG2E 1.44269504088896340736f

typedef float v2f __attribute__((ext_vector_type(2)));

constexpr int BLOCK = 256;
constexpr int SEGS  = 64;    // i-split: N/64 = 128 points per block

// R10 shell (tied-best): lane = j, wave-uniform point broadcast from LDS
// (free, m136), grid 32x64 = 2048 blocks = 8/CU. R3-calibrated issue model:
// v_exp_f32 = 16 cyc/wave on gfx950 (4 lanes/cyc). This round halves the
// VALU side with v_pk_fma_f32: two points packed per float2 lane ->
// 3 pk_fma (t) + 1 pk_fma (num) + 1 pk_add (den) per 2 pairs
// = 21 cyc/pair-wave vs 26 scalar. exp (16/pair) is the irreducible floor.
__global__ __launch_bounds__(BLOCK) void nw_partial(
    const float2* __restrict__ x,        // M x 2 query points
    const float2* __restrict__ inputs,   // N x 2 data points
    const float*  __restrict__ outputs,  // N
    const float*  __restrict__ bw,       // M
    float2*       __restrict__ partial,  // SEGS x M  (num, den)
    int N, int M)
{
    constexpr int PTS = 128;             // points per segment (N=8192/64)
    __shared__ float4 pts[PTS];          // (px, py, s, o)  2 KB

    const int tid = threadIdx.x;
    const int jg  = blockIdx.x;
    const int seg = blockIdx.y;
    const int per = (N + SEGS - 1) / SEGS;     // 128
    const int i0  = seg * per;
    const int cnt = min(per, N - i0);

    // stage this block's point segment (coalesced, once)
    for (int t = tid; t < per; t += BLOCK) {
        if (t < cnt) {
            float2 p = inputs[i0 + t];
            pts[t] = make_float4(p.x, p.y, fmaf(p.x, p.x, p.y * p.y),
                                 outputs[i0 + t]);
        } else {
            pts[t] = make_float4(0.f, 0.f, 3.0e38f, 0.f);   // c0*s -> -inf, w = 0
        }
    }

    // per-thread coefficients for its single j (k < 0 folded in)
    const int j = jg * BLOCK + tid;
    float c0 = 0.f, c1 = 0.f, c2 = 0.f, c3 = -1.0e38f;
    if (j < M) {
        float2 xj = x[j];                // lane-coalesced
        float  b  = bw[j];
        float  k  = -LOG2E / (2.0f * b * b);
        c0 = k;
        c1 = -2.0f * k * xj.x;
        c2 = -2.0f * k * xj.y;
        c3 = k * fmaf(xj.x, xj.x, xj.y * xj.y);
    }
    const v2f C0 = {c0, c0}, C1 = {c1, c1}, C2 = {c2, c2}, C3 = {c3, c3};

    __syncthreads();                     // the only barrier

    v2f NUM0 = {0.f, 0.f}, NUM1 = {0.f, 0.f};
    v2f DEN0 = {0.f, 0.f}, DEN1 = {0.f, 0.f};
    #pragma unroll 4
    for (int l = 0; l < PTS; l += 4) {   // 4 points/iter, 2 packed groups
        float4 pa = pts[l];              // wave-uniform addr -> LDS broadcast
        float4 pb = pts[l + 1];
        float4 pc = pts[l + 2];
        float4 pd = pts[l + 3];

        v2f S0 = {pa.z, pb.z}, X0 = {pa.x, pb.x}, Y0 = {pa.y, pb.y}, O0 = {pa.w, pb.w};
        v2f S1 = {pc.z, pd.z}, X1 = {pc.x, pd.x}, Y1 = {pc.y, pd.y}, O1 = {pc.w, pd.w};

        v2f T0 = __builtin_elementwise_fma(C0, S0,
                 __builtin_elementwise_fma(C1, X0,
                 __builtin_elementwise_fma(C2, Y0, C3)));   // 3 v_pk_fma_f32
        v2f T1 = __builtin_elementwise_fma(C0, S1,
                 __builtin_elementwise_fma(C1, X1,
                 __builtin_elementwise_fma(C2, Y1, C3)));

        v2f W0, W1;
        W0.x = __builtin_amdgcn_exp2f(T0.x);
        W0.y = __builtin_amdgcn_exp2f(T0.y);
        W1.x = __builtin_amdgcn_exp2f(T1.x);
        W1.y = __builtin_amdgcn_exp2f(T1.y);

        NUM0 = __builtin_elementwise_fma(W0, O0, NUM0);     // v_pk_fma_f32
        NUM1 = __builtin_elementwise_fma(W1, O1, NUM1);
        DEN0 += W0;                                         // v_pk_add_f32
        DEN1 += W1;
    }

    if (j < M) {
        float num = (NUM0.x + NUM0.y) + (NUM1.x + NUM1.y);
        float den = (DEN0.x + DEN0.y) + (DEN1.x + DEN1.y);
        partial[(size_t)seg * M + j] = make_float2(num, den);
    }
}

// Plain second dispatch (coop sync +95us R3, device fences +147us R6 —
// the dispatch boundary is the cheap grid-scope coherence point).
__global__ __launch_bounds__(BLOCK) void nw_finalize(
    const float2* __restrict__ partial,
    float*        __restrict__ out,
    int M)
{
    const int j = blockIdx.x * BLOCK + threadIdx.x;
    if (j >= M) return;
    float num = 0.f, den = 0.f;
    #pragma unroll 8
    for (int s = 0; s < SEGS; ++s) {
        float2 p = partial[(size_t)s * M + j];   // coalesced across j
        num += p.x;
        den += p.y;
    }
    out[j] = num / (den + EPS);
}

extern "C" void kernel_launch(void* const* d_in, const int* in_sizes, int n_in,
                              void* d_out, int out_size, void* d_ws, size_t ws_size,
                              hipStream_t stream) {
    // setup_inputs() dict order: x (M*2), inputs (N*2), outputs (N), bandwidth (M)
    const float2* x       = (const float2*)d_in[0];
    const float2* inputs  = (const float2*)d_in[1];
    const float*  outputs = (const float*) d_in[2];
    const float*  bwv     = (const float*) d_in[3];
    const int N = in_sizes[2];   // outputs element count
    const int M = in_sizes[3];   // bandwidth element count
    float*        out     = (float*)d_out;
    float2*       partial = (float2*)d_ws;   // SEGS * M * 8 B = 4 MB

    dim3 grid1((M + BLOCK - 1) / BLOCK, SEGS);   // 32 x 64 = 2048 blocks
    nw_partial<<<grid1, BLOCK, 0, stream>>>(x, inputs, outputs, bwv, partial, N, M);

    nw_finalize<<<dim3((M + BLOCK - 1) / BLOCK), BLOCK, 0, stream>>>(partial, out, M);
}

// Round 12
// 76.231 us; speedup vs baseline: 1.0253x; 1.0253x over previous
//
#include <hip/hip_runtime.h>

#define EPS 1e-7f
#define LOG2E 1.44269504088896340736f

constexpr int BLOCK = 1024;        // 16 waves/block
constexpr int JB    = 32;          // outputs (j) per block
constexpr int SS    = BLOCK / JB;  // 32 i-segments per block
constexpr int CHUNK = 1024;        // points staged per LDS chunk (16 KB)

// FINAL (revert to R7, best measured: 75.95us).
// Session evidence: total = ~40.5us harness d_ws poison-fill (83% HBM peak,
// memory-roofline-bound, untouchable) + ~13us fixed graph-replay overhead
// (calibrated via R5/R6: total - kernel = 52.7/53.6us) + ~23us kernel slice.
// The kernel slice was invariant across 5 delivery schemes (VMEM broadcast,
// per-lane LDS, JT-tiled LDS, wave-uniform LDS broadcast, global strided) and
// 2 issue-count reductions (8x delivery cut R9, packed-VALU R11) — pinned by
// ramp-clock exp/VALU issue + dispatch latency, not by anything source
// controls. Grid-scope alternatives measured catastrophic: coop grid.sync
// +95us (R3), device-scope __threadfence +147us (R6).
__global__ __launch_bounds__(BLOCK, 4) void nw_block(
    const float2* __restrict__ x,        // M x 2 query points
    const float2* __restrict__ inputs,   // N x 2 data points
    const float*  __restrict__ outputs,  // N
    const float*  __restrict__ bw,       // M
    float*        __restrict__ out,      // M
    int N, int M)
{
    __shared__ float4 pts[CHUNK];        // (px, py, s, o)
    __shared__ float2 red[SS][JB];       // per-(segment, jj) partials

    const int tid = threadIdx.x;
    const int jj  = tid & (JB - 1);
    const int ss  = tid / JB;
    const int j   = blockIdx.x * JB + jj;

    float c0 = 0.f, c1 = 0.f, c2 = 0.f, c3 = 0.f;
    if (j < M) {
        float2 xj = x[j];
        float  b  = bw[j];
        float  k  = -LOG2E / (2.0f * b * b);     // < 0
        c0 = k;
        c1 = -2.0f * k * xj.x;
        c2 = -2.0f * k * xj.y;
        c3 = k * fmaf(xj.x, xj.x, xj.y * xj.y);
    }

    float num = 0.f, den = 0.f;
    for (int base = 0; base < N; base += CHUNK) {
        const int cnt = min(CHUNK, N - base);
        // stage one chunk: 1024 threads, one point each (coalesced)
        if (tid < cnt) {
            float2 p = inputs[base + tid];
            float  o = outputs[base + tid];
            pts[tid] = make_float4(p.x, p.y, fmaf(p.x, p.x, p.y * p.y), o);
        } else if (tid < CHUNK) {
            pts[tid] = make_float4(0.f, 0.f, 3.0e38f, 0.f);  // pad: w -> 0
        }
        __syncthreads();

        // each thread: its contiguous CHUNK/SS = 32 points of this chunk
        const float4* my = &pts[ss * (CHUNK / SS)];
        #pragma unroll 8
        for (int l = 0; l < CHUNK / SS; ++l) {
            float4 p = my[l];                        // ds_read_b128
            float  t = fmaf(c0, p.z, fmaf(c1, p.x, fmaf(c2, p.y, c3)));
            float  w = __builtin_amdgcn_exp2f(t);
            num = fmaf(w, p.w, num);
            den += w;
        }
        __syncthreads();
    }

    // block-local cross-segment reduction
    red[ss][jj] = make_float2(num, den);
    __syncthreads();
    if (tid < JB) {                                  // ss == 0, jj == tid
        float n = 0.f, d = 0.f;
        #pragma unroll
        for (int s = 0; s < SS; ++s) {
            n += red[s][tid].x;
            d += red[s][tid].y;
        }
        const int jo = blockIdx.x * JB + tid;
        if (jo < M) out[jo] = n / (d + EPS);
    }
}

extern "C" void kernel_launch(void* const* d_in, const int* in_sizes, int n_in,
                              void* d_out, int out_size, void* d_ws, size_t ws_size,
                              hipStream_t stream) {
    // setup_inputs() dict order: x (M*2), inputs (N*2), outputs (N), bandwidth (M)
    const float2* x       = (const float2*)d_in[0];
    const float2* inputs  = (const float2*)d_in[1];
    const float*  outputs = (const float*) d_in[2];
    const float*  bwv     = (const float*) d_in[3];
    const int N = in_sizes[2];   // outputs element count
    const int M = in_sizes[3];   // bandwidth element count
    float*        out     = (float*)d_out;

    dim3 grid((M + JB - 1) / JB);    // 256 blocks @ M=8192 -> 1 block/CU
    nw_block<<<grid, BLOCK, 0, stream>>>(x, inputs, outputs, bwv, out, N, M);
}